// Round 26
// baseline (128.954 us; speedup 1.0000x reference)
//
#include <hip/hip_runtime.h>
#include <hip/hip_bf16.h>
#include <stdint.h>

#define L_SEQ  4096
#define H_DIM  512
#define N_ST   64
#define N_B    8
#define N_CH   16
#define T_CH   256
#define K_GEMM 1024

typedef float  f32x4  __attribute__((ext_vector_type(4)));
typedef __bf16 bf16x8 __attribute__((ext_vector_type(8)));
typedef __bf16 bf16x4 __attribute__((ext_vector_type(4)));
typedef unsigned short u16x8 __attribute__((ext_vector_type(8)));
typedef unsigned long long ull;

#define GLOAD16(g, l) __builtin_amdgcn_global_load_lds( \
    (const __attribute__((address_space(1))) void*)(g), \
    (__attribute__((address_space(3))) void*)(l), 16, 0, 0)

// ---------------- k_ut: u transpose + W->bf16 + (blk>=8192) params/taps ----------------
__global__ __launch_bounds__(256) void k_ut(
    const float* __restrict__ u, __bf16* __restrict__ ut,
    const float* __restrict__ W, __bf16* __restrict__ Wbf,
    const float* __restrict__ A_log, const float* __restrict__ Bv,
    const float* __restrict__ C, const float* __restrict__ log_dt,
    const float* __restrict__ A_log_r, const float* __restrict__ B_r,
    const float* __restrict__ C_r,
    float* __restrict__ kk, float* __restrict__ pLG,
    float* __restrict__ pCB, float* __restrict__ pPW)
{
    __shared__ float tl[32][65];
    __shared__ float scb[64], slg[64];
    int blk = blockIdx.x;
    int t = threadIdx.x;

    if (blk >= 8192) {               // ---- fused k_kk: params + conv taps ----
        int dirh = blk - 8192;       // 0..1023
        int dir  = dirh >> 9, h = dirh & 511;
        int d = t;
        if (d < 64) {
            int n = d;
            float dt = expf(log_dt[h]);
            const float* Al = dir ? A_log_r : A_log;
            const float* Bp = dir ? B_r    : Bv;
            const float* Cp = dir ? C_r    : C;
            float eA = expf(Al[h * N_ST + n]);
            float Ab = expf(-dt * eA);
            float Bb = (1.0f - Ab) / eA * Bp[h * N_ST + n];
            float cb = Cp[h * N_ST + n] * Bb;
            float lg = -dt * eA * 1.44269504088896f;
            scb[n] = cb; slg[n] = lg;
            pCB[dirh * 64 + n] = cb;
            pLG[dirh * 64 + n] = lg;
            pPW[dirh * 64 + n] = expf(-dt * eA * (float)T_CH);
        }
        __syncthreads();
        float s = 0.f;
        #pragma unroll
        for (int n = 0; n < 64; ++n) s += scb[n] * exp2f((float)d * slg[n]);
        kk[dirh * 256 + d] = s;
        return;
    }

    int lt = blk & 127, ht = (blk >> 7) & 7, b = blk >> 10;
    int ho = t & 63, li = t >> 6;
    #pragma unroll
    for (int it = 0; it < 8; ++it) {
        int l = it * 4 + li;
        tl[l][ho] = u[(size_t)(b * L_SEQ + lt * 32 + l) * H_DIM + ht * 64 + ho];
    }
    if (blk < 2048) {                 // fused W f32->bf16
        int i = blk * 256 + t;
        Wbf[i] = (__bf16)W[i];
    }
    __syncthreads();
    int hh = t >> 2, lrun = (t & 3) * 8;
    bf16x8 v;
    #pragma unroll
    for (int i = 0; i < 8; ++i) v[i] = (__bf16)tl[lrun + i][hh];
    *(bf16x8*)(ut + (size_t)(ht * 64 + hh) * 32768 + b * 4096 + lt * 32 + lrun) = v;
}

// ---------------- K1 v5 (R25-verified): MFMA states + fused scan, hf-dbuf staging ----------------
__global__ __launch_bounds__(512, 2) void k_state(
    const __bf16* __restrict__ ut, const float* __restrict__ pLG,
    const float* __restrict__ pPW, __bf16* __restrict__ S2)
{
    __shared__ __bf16 uts[32768];   // 64 KB: both halves
    int h = blockIdx.x;
    int t = threadIdx.x;
    int lane = t & 63, w = t >> 6;
    int lr = lane & 15, lg = lane >> 4;
    int dir = w >> 2, mtile = w & 3;

    #pragma unroll
    for (int hf = 0; hf < 2; ++hf)
        #pragma unroll
        for (int i = 0; i < 4; ++i) {
            int chunk = i * 512 + t;       // 0..2047
            int col   = chunk >> 5;
            int l8    = (chunk & 31) << 3;
            int l8s   = l8 ^ ((col & 7) << 3);
            GLOAD16(ut + (size_t)h * 32768 + (hf * 64 + col) * 256 + l8s,
                    (char*)uts + hf * 32768 + chunk * 16);
        }

    float s = pLG[(size_t)(dir * 512 + h) * 64 + mtile * 16 + lr];
    f32x4 pw4 = *(const f32x4*)(pPW + (size_t)(dir * 512 + h) * 64 + mtile * 16 + lg * 4);

    bf16x8 Mf[8];
    #pragma unroll
    for (int kk = 0; kk < 8; ++kk) {
        #pragma unroll
        for (int jj = 0; jj < 8; ++jj) {
            int j = kk * 32 + lg * 8 + jj;
            float e = dir ? (float)j : (float)(255 - j);
            Mf[kk][jj] = (__bf16)exp2f(e * s);
        }
    }

    asm volatile("s_waitcnt vmcnt(0)" ::: "memory");
    __builtin_amdgcn_sched_barrier(0);
    __builtin_amdgcn_s_barrier();
    __builtin_amdgcn_sched_barrier(0);

    #pragma unroll
    for (int hf = 0; hf < 2; ++hf) {
        char* ub = (char*)uts + hf * 32768;

        #pragma unroll
        for (int ntile = 0; ntile < 4; ++ntile) {
            f32x4 acc = {};
            #pragma unroll
            for (int kk = 0; kk < 8; ++kk) {
                int col = ntile * 16 + lr;
                bf16x8 bv = *(const bf16x8*)(ub + col * 512
                             + (((kk * 4 + lg) ^ (col & 7)) << 4));
                acc = __builtin_amdgcn_mfma_f32_16x16x32_bf16(Mf[kk], bv, acc, 0, 0, 0);
            }
            f32x4 X;
            if (dir == 0) {
                f32x4 incl = acc;
                float p0 = pw4[0], p1 = pw4[1], p2 = pw4[2], p3 = pw4[3];
                #pragma unroll
                for (int st = 1; st <= 8; st <<= 1) {
                    float u0 = __shfl(incl[0], (lane - st) & 63);
                    float u1 = __shfl(incl[1], (lane - st) & 63);
                    float u2 = __shfl(incl[2], (lane - st) & 63);
                    float u3 = __shfl(incl[3], (lane - st) & 63);
                    if (lr >= st) {
                        incl[0] = fmaf(p0, u0, incl[0]);
                        incl[1] = fmaf(p1, u1, incl[1]);
                        incl[2] = fmaf(p2, u2, incl[2]);
                        incl[3] = fmaf(p3, u3, incl[3]);
                    }
                    p0 *= p0; p1 *= p1; p2 *= p2; p3 *= p3;
                }
                #pragma unroll
                for (int r = 0; r < 4; ++r) {
                    float sh = __shfl(incl[r], (lane - 1) & 63);
                    X[r] = (lr == 0) ? 0.f : sh;
                }
            } else {
                f32x4 incl = acc;
                float p0 = pw4[0], p1 = pw4[1], p2 = pw4[2], p3 = pw4[3];
                #pragma unroll
                for (int st = 1; st <= 8; st <<= 1) {
                    float u0 = __shfl(incl[0], (lane + st) & 63);
                    float u1 = __shfl(incl[1], (lane + st) & 63);
                    float u2 = __shfl(incl[2], (lane + st) & 63);
                    float u3 = __shfl(incl[3], (lane + st) & 63);
                    if (lr <= 15 - st) {
                        incl[0] = fmaf(p0, u0, incl[0]);
                        incl[1] = fmaf(p1, u1, incl[1]);
                        incl[2] = fmaf(p2, u2, incl[2]);
                        incl[3] = fmaf(p3, u3, incl[3]);
                    }
                    p0 *= p0; p1 *= p1; p2 *= p2; p3 *= p3;
                }
                #pragma unroll
                for (int r = 0; r < 4; ++r) {
                    float sh = __shfl(incl[r], (lane + 1) & 63);
                    X[r] = (lr == 15) ? 0.f : sh;
                }
            }
            int colg = hf * 64 + ntile * 16 + lr;   // = b*16 + c
            int nq   = mtile * 4 + lg;
            bf16x4 o;
            #pragma unroll
            for (int r = 0; r < 4; ++r) o[r] = (__bf16)X[r];
            *(bf16x4*)(S2 + ((size_t)((dir * 512 + h) * 16 + nq) * 128 + colg) * 4) = o;
        }
    }
}

// ---------------- k_conv v7: both dirs' tables hoisted; barrier-free dual-dir compute ----------------
__global__ __launch_bounds__(512, 2) void k_conv(
    const float* __restrict__ kk, const float* __restrict__ pLG,
    const float* __restrict__ pCB, const float* __restrict__ Dv,
    const __bf16* __restrict__ ut, const __bf16* __restrict__ S,
    __bf16* __restrict__ ycT)
{
    __shared__ __bf16 uts[32768];           // 64 KB: both halves
    __shared__ ull kkq8[2][544];            // 8.5 KB: both dirs
    __shared__ unsigned short asc[2][548];  // 2.14 KB
    __shared__ float slg[2][64], scb[2][64];
    int h = blockIdx.x;
    int t = threadIdx.x;
    int lane = t & 63, w = t >> 6;
    int lr = lane & 15, lg = lane >> 4;

    // ---- stage BOTH halves once ----
    #pragma unroll
    for (int hf = 0; hf < 2; ++hf)
        #pragma unroll
        for (int i = 0; i < 4; ++i) {
            int chunk = i * 512 + t;          // 0..2047
            int col   = chunk >> 5;
            int l8    = (chunk & 31) << 3;
            int l8s   = l8 ^ ((col & 7) << 3);
            GLOAD16(ut + (size_t)h * 32768 + (hf * 64 + col) * 256 + l8s,
                    (char*)uts + hf * 32768 + chunk * 16);
        }

    float Dh = Dv[h];

    // ---- build BOTH dirs' taps + params UNDER the staging flight ----
    #pragma unroll
    for (int dir = 0; dir < 2; ++dir) {
        int dirh = dir * 512 + h;
        for (int i = t; i < 548; i += 512) {
            int d = dir ? (i - 272) : (271 - i);
            float kv = (d >= 0 && d < 256) ? kk[dirh * 256 + d] : 0.f;
            asc[dir][i] = __builtin_bit_cast(unsigned short, (__bf16)kv);
        }
        if (t < 64)       slg[dir][t]      = pLG[dirh * 64 + t];
        else if (t < 128) scb[dir][t - 64] = pCB[dirh * 64 + (t - 64)];
    }
    asm volatile("s_waitcnt lgkmcnt(0)" ::: "memory");
    __builtin_amdgcn_sched_barrier(0);
    __builtin_amdgcn_s_barrier();
    __builtin_amdgcn_sched_barrier(0);
    #pragma unroll
    for (int dir = 0; dir < 2; ++dir)
        for (int i = t; i < 544; i += 512)
            kkq8[dir][i] = (ull)asc[dir][i] | ((ull)asc[dir][i+1] << 16)
                         | ((ull)asc[dir][i+2] << 32) | ((ull)asc[dir][i+3] << 48);

    // gvv for both dirs (VALU under staging flight)
    bf16x8 gvv[2][2][2];
    #pragma unroll
    for (int dir = 0; dir < 2; ++dir)
        #pragma unroll
        for (int nt = 0; nt < 2; ++nt)
            #pragma unroll
            for (int mf = 0; mf < 2; ++mf) {
                int rt = mf ? (15 - w) : w;
                int l  = rt * 16 + lr;
                float e = dir ? (float)(256 - l) : (float)(l + 1);
                #pragma unroll
                for (int j = 0; j < 8; ++j) {
                    int n = nt * 32 + lg * 8 + j;
                    gvv[dir][nt][mf][j] = (__bf16)(scb[dir][n] * exp2f(e * slg[dir][n]));
                }
            }

    // single drain: staged uts + kkq8 writes visible; then NO more barriers
    asm volatile("s_waitcnt vmcnt(0) lgkmcnt(0)" ::: "memory");
    __builtin_amdgcn_sched_barrier(0);
    __builtin_amdgcn_s_barrier();
    __builtin_amdgcn_sched_barrier(0);

    const int rt0 = w, rt1 = 15 - w;

    #pragma unroll
    for (int dir = 0; dir < 2; ++dir) {
        int dirh = dir * 512 + h;
        const ull* kq = kkq8[dir];
        const int sb0 = (dir ? 272 : 271) + lg * 8 - rt0 * 16 - lr;
        const int sb1 = (dir ? 272 : 271) + lg * 8 - rt1 * 16 - lr;
        const int jhi0 = dir ? 8 : ((rt0 >> 1) + 1);
        const int jlo1 = dir ? (rt1 >> 1) : 0;
        const int jbeg = dir ? (rt0 >> 1) : 0;
        const int jend = dir ? 8 : (((rt1) >> 1) + 1);

        #pragma unroll
        for (int hf = 0; hf < 2; ++hf) {
            char* ub = (char*)uts + hf * 32768;

            f32x4 acc[2][4] = {};

            for (int jt = jbeg; jt < jend; ++jt) {
                bf16x8 bv[4];
                #pragma unroll
                for (int n = 0; n < 4; ++n) {
                    int col = n * 16 + lr;
                    bv[n] = *(const bf16x8*)(ub + col * 512
                              + (((jt * 4 + lg) ^ (col & 7)) << 4));
                }
                if (dir ? true : (jt < jhi0)) {
                    int si = sb0 + jt * 32;
                    ull lo = kq[si], hi = kq[si + 4];
                    bf16x8 av;
                    ((ull*)&av)[0] = lo; ((ull*)&av)[1] = hi;
                    __builtin_amdgcn_s_setprio(1);
                    #pragma unroll
                    for (int n = 0; n < 4; ++n)
                        acc[0][n] = __builtin_amdgcn_mfma_f32_16x16x32_bf16(av, bv[n], acc[0][n], 0, 0, 0);
                    __builtin_amdgcn_s_setprio(0);
                }
                if (dir ? (jt >= jlo1) : true) {
                    int si = sb1 + jt * 32;
                    ull lo = kq[si], hi = kq[si + 4];
                    bf16x8 av;
                    ((ull*)&av)[0] = lo; ((ull*)&av)[1] = hi;
                    __builtin_amdgcn_s_setprio(1);
                    #pragma unroll
                    for (int n = 0; n < 4; ++n)
                        acc[1][n] = __builtin_amdgcn_mfma_f32_16x16x32_bf16(av, bv[n], acc[1][n], 0, 0, 0);
                    __builtin_amdgcn_s_setprio(0);
                }
            }

            #pragma unroll
            for (int nt = 0; nt < 2; ++nt) {
                bf16x8 bs[4];
                #pragma unroll
                for (int n = 0; n < 4; ++n) {
                    int colg = (hf * 4 + n) * 16 + lr;
                    int nq0  = nt * 8 + lg * 2;
                    const __bf16* sp = S + ((size_t)((dir * 512 + h) * 16 + nq0) * 128 + colg) * 4;
                    bf16x4 s0 = *(const bf16x4*)(sp);
                    bf16x4 s1 = *(const bf16x4*)(sp + 512);
                    #pragma unroll
                    for (int j = 0; j < 4; ++j) { bs[n][j] = s0[j]; bs[n][4 + j] = s1[j]; }
                }
                __builtin_amdgcn_s_setprio(1);
                #pragma unroll
                for (int mf = 0; mf < 2; ++mf)
                    #pragma unroll
                    for (int n = 0; n < 4; ++n)
                        acc[mf][n] = __builtin_amdgcn_mfma_f32_16x16x32_bf16(gvv[dir][nt][mf], bs[n], acc[mf][n], 0, 0, 0);
                __builtin_amdgcn_s_setprio(0);
            }

            #pragma unroll
            for (int mf = 0; mf < 2; ++mf) {
                int rt = mf ? rt1 : rt0;
                int l0 = rt * 16 + lg * 4;
                #pragma unroll
                for (int n = 0; n < 4; ++n) {
                    int col = n * 16 + lr;
                    bf16x4 uv = *(const bf16x4*)(ub + col * 512
                                 + ((((l0 >> 3) ^ (col & 7)) << 4) | ((l0 & 7) * 2)));
                    bf16x4 o;
                    #pragma unroll
                    for (int r = 0; r < 4; ++r)
                        o[r] = (__bf16)(acc[mf][n][r] + Dh * (float)uv[r]);
                    *(bf16x4*)(ycT + (size_t)dirh * 32768 + (hf * 64 + col) * 256 + l0) = o;
                }
            }
        }
    }
}

// ---------------- K4 v11 (R24-verified): single-barrier/iter, 2A+4B ring ----------------
__global__ __launch_bounds__(256, 2) void k_gemm(
    const __bf16* __restrict__ ycT, const __bf16* __restrict__ B,
    const float* __restrict__ bias, float* __restrict__ out)
{
    __shared__ __bf16 As[2][4][128][8];    // 16 KB
    __shared__ __bf16 Bs[4][256][32];      // 64 KB
    int t  = threadIdx.x;
    int l  = t & 63, w = t >> 6;
    int lr = l & 15, lg = l >> 4;
    int bid   = blockIdx.y * 2 + blockIdx.x;
    int swzid = (bid & 7) * 64 + (bid >> 3);
    int mBase = (swzid >> 1) * 128;
    int nBase = (swzid & 1) * 256;
    int wr = (w >> 1) * 64, wc = (w & 1) * 128;

    int sT  = t & 15;           // m-octet
    int sp  = t >> 4;           // k-pair 0..15 (k = 2sp, 2sp+1)
    int swz  = (sT & 7) << 4;
    int kgrp = sp >> 2;
    int keb  = (sp & 3) * 4;

    f32x4 acc[4][8] = {};
    const __bf16* aptr = ycT + mBase + sT * 8;

#define STAGE_A(abuf, va0, va1) do { \
    char* AsB_ = (char*)&As[0][0][0][0] + (abuf) * 8192; \
    _Pragma("unroll") \
    for (int i = 0; i < 8; ++i) { \
        unsigned v_ = (unsigned)(unsigned short)(va0)[i] \
                    | ((unsigned)(unsigned short)(va1)[i] << 16); \
        int off_ = ((kgrp * 128 + sT * 8 + i) * 16 + keb) ^ swz; \
        *(unsigned*)(AsB_ + off_) = v_; \
    } } while (0)

#define STAGE_B(bbuf, kt_) do { \
    char* BsB_ = (char*)&Bs[0][0][0] + (bbuf) * 16384; \
    _Pragma("unroll") \
    for (int i = 0; i < 4; ++i) { \
        int chunk_ = i * 256 + t; \
        int row_ = chunk_ >> 2, kq_ = chunk_ & 3; \
        int kqs_ = kq_ ^ ((row_ >> 1) & 3); \
        GLOAD16(B + (size_t)(nBase + row_) * K_GEMM + (kt_) + kqs_ * 8, \
                BsB_ + chunk_ * 16); \
    } } while (0)

#define COMPUTE(abuf, bbuf) do { \
    char* AsB_ = (char*)&As[0][0][0][0] + (abuf) * 8192; \
    char* BsB_ = (char*)&Bs[0][0][0] + (bbuf) * 16384; \
    bf16x8 af_[4], bfv_[8]; \
    _Pragma("unroll") \
    for (int m = 0; m < 4; ++m) { \
        int row_ = wr + m * 16 + lr; \
        int off_ = ((lg * 128 + row_) * 16) ^ (((row_ >> 3) & 7) << 4); \
        af_[m] = *(const bf16x8*)(AsB_ + off_); \
    } \
    _Pragma("unroll") \
    for (int n = 0; n < 8; ++n) { \
        int row_ = wc + n * 16 + lr; \
        bfv_[n] = *(const bf16x8*)(BsB_ + row_ * 64 \
                    + ((lg * 16) ^ (((row_ >> 1) & 3) << 4))); \
    } \
    __builtin_amdgcn_s_setprio(1); \
    _Pragma("unroll") \
    for (int m = 0; m < 4; ++m) \
        _Pragma("unroll") \
        for (int n = 0; n < 8; ++n) \
            acc[m][n] = __builtin_amdgcn_mfma_f32_16x16x32_bf16(af_[m], bfv_[n], acc[m][n], 0, 0, 0); \
    __builtin_amdgcn_s_setprio(0); \
    } while (0)

    // ---- prologue: A-regs(0); B(0)->buf0, B(1)->buf1 issued ----
    u16x8 a0 = *(const u16x8*)(aptr + (size_t)(2 * sp) * 32768);
    u16x8 a1 = *(const u16x8*)(aptr + (size_t)(2 * sp + 1) * 32768);
    STAGE_B(0, 0);
    STAGE_B(1, 32);

    int ab = 0;
    for (int i = 0; i < 30; ++i) {                 // kt = 32*i
        int kt = i * 32;
        STAGE_A(ab, a0, a1);                       // waits prev A-regs (compiler vmcnt)
        a0 = *(const u16x8*)(aptr + (size_t)(kt + 32 + 2 * sp) * 32768);
        a1 = *(const u16x8*)(aptr + (size_t)(kt + 32 + 2 * sp + 1) * 32768);
        STAGE_B((i + 2) & 3, kt + 64);
        asm volatile("s_waitcnt vmcnt(10) lgkmcnt(0)" ::: "memory");
        __builtin_amdgcn_sched_barrier(0);
        __builtin_amdgcn_s_barrier();              // the ONLY barrier this iter
        __builtin_amdgcn_sched_barrier(0);
        COMPUTE(ab, i & 3);
        ab ^= 1;
    }
    // ---- peel i=30 (kt=960): no new B ----
    STAGE_A(ab, a0, a1);
    a0 = *(const u16x8*)(aptr + (size_t)(992 + 2 * sp) * 32768);
    a1 = *(const u16x8*)(aptr + (size_t)(992 + 2 * sp + 1) * 32768);
    asm volatile("s_waitcnt vmcnt(6) lgkmcnt(0)" ::: "memory");
    __builtin_amdgcn_sched_barrier(0);
    __builtin_amdgcn_s_barrier();
    __builtin_amdgcn_sched_barrier(0);
    COMPUTE(ab, 30 & 3);
    ab ^= 1;
    // ---- peel i=31 (kt=992): drain all ----
    STAGE_A(ab, a0, a1);
    asm volatile("s_waitcnt vmcnt(0) lgkmcnt(0)" ::: "memory");
    __builtin_amdgcn_sched_barrier(0);
    __builtin_amdgcn_s_barrier();
    __builtin_amdgcn_sched_barrier(0);
    COMPUTE(ab, 31 & 3);

#undef STAGE_A
#undef STAGE_B
#undef COMPUTE

    #pragma unroll
    for (int n = 0; n < 8; ++n) {
        int colg = nBase + wc + n * 16 + lr;
        float bv = bias[colg];
        #pragma unroll
        for (int m = 0; m < 4; ++m) {
            int rowg = mBase + wr + m * 16 + lg * 4;
            #pragma unroll
            for (int r = 0; r < 4; ++r)
                out[(size_t)(rowg + r) * H_DIM + colg] = acc[m][n][r] + bv;
        }
    }
}

extern "C" void kernel_launch(void* const* d_in, const int* in_sizes, int n_in,
                              void* d_out, int out_size, void* d_ws, size_t ws_size,
                              hipStream_t stream)
{
    const float* u       = (const float*)d_in[0];
    const float* A_log   = (const float*)d_in[1];
    const float* Bv      = (const float*)d_in[2];
    const float* C       = (const float*)d_in[3];
    const float* D       = (const float*)d_in[4];
    const float* log_dt  = (const float*)d_in[5];
    const float* A_log_r = (const float*)d_in[6];
    const float* B_r     = (const float*)d_in[7];
    const float* C_r     = (const float*)d_in[8];
    const float* W_bi    = (const float*)d_in[9];
    const float* b_bi    = (const float*)d_in[10];
    float* out = (float*)d_out;

    char* ws = (char*)d_ws;
    float* pCB  = (float*)(ws + 0x040000);
    float* pPW  = (float*)(ws + 0x080000);
    float* pLG  = (float*)(ws + 0x0C0000);
    float* kk   = (float*)(ws + 0x100000);   // 1 MiB
    __bf16* Wbf = (__bf16*)(ws + 0x200000);  // 1 MiB
    __bf16* S   = (__bf16*)(ws + 0x300000);  // 16 MiB (S2 layout, scanned)
    __bf16* ut  = (__bf16*)(ws + 0x1300000); // 32 MiB
    __bf16* ycT = (__bf16*)(ws + 0x3300000); // 64 MiB  (end 115 MiB)

    k_ut   <<<9216, 256, 0, stream>>>(u, ut, W_bi, Wbf,
                                      A_log, Bv, C, log_dt, A_log_r, B_r, C_r,
                                      kk, pLG, pCB, pPW);
    k_state<<<512,  512, 0, stream>>>(ut, pLG, pPW, S);
    k_conv <<<512,  512, 0, stream>>>(kk, pLG, pCB, D, ut, S, ycT);
    dim3 g(2, 256);
    k_gemm <<<g,    256, 0, stream>>>(ycT, Wbf, b_bi, out);
}

// Round 27
// 123.826 us; speedup vs baseline: 1.0414x; 1.0414x over previous
//
#include <hip/hip_runtime.h>
#include <hip/hip_bf16.h>
#include <stdint.h>

#define L_SEQ  4096
#define H_DIM  512
#define N_ST   64
#define N_B    8
#define N_CH   16
#define T_CH   256
#define K_GEMM 1024

typedef float  f32x4  __attribute__((ext_vector_type(4)));
typedef __bf16 bf16x8 __attribute__((ext_vector_type(8)));
typedef __bf16 bf16x4 __attribute__((ext_vector_type(4)));
typedef unsigned short u16x8 __attribute__((ext_vector_type(8)));
typedef unsigned long long ull;

#define GLOAD16(g, l) __builtin_amdgcn_global_load_lds( \
    (const __attribute__((address_space(1))) void*)(g), \
    (__attribute__((address_space(3))) void*)(l), 16, 0, 0)

// ---------------- k_ut: u transpose + W->bf16 + (blk>=8192) params/taps ----------------
__global__ __launch_bounds__(256) void k_ut(
    const float* __restrict__ u, __bf16* __restrict__ ut,
    const float* __restrict__ W, __bf16* __restrict__ Wbf,
    const float* __restrict__ A_log, const float* __restrict__ Bv,
    const float* __restrict__ C, const float* __restrict__ log_dt,
    const float* __restrict__ A_log_r, const float* __restrict__ B_r,
    const float* __restrict__ C_r,
    float* __restrict__ kk, float* __restrict__ pLG,
    float* __restrict__ pCB, float* __restrict__ pPW)
{
    __shared__ float tl[32][65];
    __shared__ float scb[64], slg[64];
    int blk = blockIdx.x;
    int t = threadIdx.x;

    if (blk >= 8192) {               // ---- fused k_kk: params + conv taps ----
        int dirh = blk - 8192;       // 0..1023
        int dir  = dirh >> 9, h = dirh & 511;
        int d = t;
        if (d < 64) {
            int n = d;
            float dt = expf(log_dt[h]);
            const float* Al = dir ? A_log_r : A_log;
            const float* Bp = dir ? B_r    : Bv;
            const float* Cp = dir ? C_r    : C;
            float eA = expf(Al[h * N_ST + n]);
            float Ab = expf(-dt * eA);
            float Bb = (1.0f - Ab) / eA * Bp[h * N_ST + n];
            float cb = Cp[h * N_ST + n] * Bb;
            float lg = -dt * eA * 1.44269504088896f;
            scb[n] = cb; slg[n] = lg;
            pCB[dirh * 64 + n] = cb;
            pLG[dirh * 64 + n] = lg;
            pPW[dirh * 64 + n] = expf(-dt * eA * (float)T_CH);
        }
        __syncthreads();
        float s = 0.f;
        #pragma unroll
        for (int n = 0; n < 64; ++n) s += scb[n] * exp2f((float)d * slg[n]);
        kk[dirh * 256 + d] = s;
        return;
    }

    int lt = blk & 127, ht = (blk >> 7) & 7, b = blk >> 10;
    int ho = t & 63, li = t >> 6;
    #pragma unroll
    for (int it = 0; it < 8; ++it) {
        int l = it * 4 + li;
        tl[l][ho] = u[(size_t)(b * L_SEQ + lt * 32 + l) * H_DIM + ht * 64 + ho];
    }
    if (blk < 2048) {                 // fused W f32->bf16
        int i = blk * 256 + t;
        Wbf[i] = (__bf16)W[i];
    }
    __syncthreads();
    int hh = t >> 2, lrun = (t & 3) * 8;
    bf16x8 v;
    #pragma unroll
    for (int i = 0; i < 8; ++i) v[i] = (__bf16)tl[lrun + i][hh];
    *(bf16x8*)(ut + (size_t)(ht * 64 + hh) * 32768 + b * 4096 + lt * 32 + lrun) = v;
}

// ---------------- K1 v3 (R24-verified): per-chunk end states via MFMA + fused scan ----------------
__global__ __launch_bounds__(512, 2) void k_state(
    const __bf16* __restrict__ ut, const float* __restrict__ pLG,
    const float* __restrict__ pPW, __bf16* __restrict__ S2)
{
    __shared__ __bf16 uts[16384];   // 32 KB half-slab
    int h = blockIdx.x;
    int t = threadIdx.x;
    int lane = t & 63, w = t >> 6;
    int lr = lane & 15, lg = lane >> 4;
    int dir = w >> 2, mtile = w & 3;

    float s = pLG[(size_t)(dir * 512 + h) * 64 + mtile * 16 + lr];
    f32x4 pw4 = *(const f32x4*)(pPW + (size_t)(dir * 512 + h) * 64 + mtile * 16 + lg * 4);

    bf16x8 Mf[8];
    #pragma unroll
    for (int kk = 0; kk < 8; ++kk) {
        #pragma unroll
        for (int jj = 0; jj < 8; ++jj) {
            int j = kk * 32 + lg * 8 + jj;
            float e = dir ? (float)j : (float)(255 - j);
            Mf[kk][jj] = (__bf16)exp2f(e * s);
        }
    }

    for (int hf = 0; hf < 2; ++hf) {
        if (hf) __syncthreads();
        #pragma unroll
        for (int i = 0; i < 4; ++i) {
            int chunk = i * 512 + t;       // 0..2047
            int col   = chunk >> 5;
            int l8    = (chunk & 31) << 3;
            int l8s   = l8 ^ ((col & 7) << 3);
            GLOAD16(ut + (size_t)h * 32768 + (hf * 64 + col) * 256 + l8s,
                    (char*)uts + chunk * 16);
        }
        __syncthreads();

        #pragma unroll
        for (int ntile = 0; ntile < 4; ++ntile) {
            f32x4 acc = {};
            #pragma unroll
            for (int kk = 0; kk < 8; ++kk) {
                int col = ntile * 16 + lr;
                bf16x8 bv = *(const bf16x8*)((char*)uts + col * 512
                             + (((kk * 4 + lg) ^ (col & 7)) << 4));
                acc = __builtin_amdgcn_mfma_f32_16x16x32_bf16(Mf[kk], bv, acc, 0, 0, 0);
            }
            f32x4 X;
            if (dir == 0) {
                f32x4 incl = acc;
                float p0 = pw4[0], p1 = pw4[1], p2 = pw4[2], p3 = pw4[3];
                #pragma unroll
                for (int st = 1; st <= 8; st <<= 1) {
                    float u0 = __shfl(incl[0], (lane - st) & 63);
                    float u1 = __shfl(incl[1], (lane - st) & 63);
                    float u2 = __shfl(incl[2], (lane - st) & 63);
                    float u3 = __shfl(incl[3], (lane - st) & 63);
                    if (lr >= st) {
                        incl[0] = fmaf(p0, u0, incl[0]);
                        incl[1] = fmaf(p1, u1, incl[1]);
                        incl[2] = fmaf(p2, u2, incl[2]);
                        incl[3] = fmaf(p3, u3, incl[3]);
                    }
                    p0 *= p0; p1 *= p1; p2 *= p2; p3 *= p3;
                }
                #pragma unroll
                for (int r = 0; r < 4; ++r) {
                    float sh = __shfl(incl[r], (lane - 1) & 63);
                    X[r] = (lr == 0) ? 0.f : sh;
                }
            } else {
                f32x4 incl = acc;
                float p0 = pw4[0], p1 = pw4[1], p2 = pw4[2], p3 = pw4[3];
                #pragma unroll
                for (int st = 1; st <= 8; st <<= 1) {
                    float u0 = __shfl(incl[0], (lane + st) & 63);
                    float u1 = __shfl(incl[1], (lane + st) & 63);
                    float u2 = __shfl(incl[2], (lane + st) & 63);
                    float u3 = __shfl(incl[3], (lane + st) & 63);
                    if (lr <= 15 - st) {
                        incl[0] = fmaf(p0, u0, incl[0]);
                        incl[1] = fmaf(p1, u1, incl[1]);
                        incl[2] = fmaf(p2, u2, incl[2]);
                        incl[3] = fmaf(p3, u3, incl[3]);
                    }
                    p0 *= p0; p1 *= p1; p2 *= p2; p3 *= p3;
                }
                #pragma unroll
                for (int r = 0; r < 4; ++r) {
                    float sh = __shfl(incl[r], (lane + 1) & 63);
                    X[r] = (lr == 15) ? 0.f : sh;
                }
            }
            int colg = hf * 64 + ntile * 16 + lr;   // = b*16 + c
            int nq   = mtile * 4 + lg;
            bf16x4 o;
            #pragma unroll
            for (int r = 0; r < 4; ++r) o[r] = (__bf16)X[r];
            *(bf16x4*)(S2 + ((size_t)((dir * 512 + h) * 16 + nq) * 128 + colg) * 4) = o;
        }
    }
}

// ---------------- k_conv v6 (R24-verified): one block per h, both dirs ----------------
__global__ __launch_bounds__(512, 2) void k_conv(
    const float* __restrict__ kk, const float* __restrict__ pLG,
    const float* __restrict__ pCB, const float* __restrict__ Dv,
    const __bf16* __restrict__ ut, const __bf16* __restrict__ S,
    __bf16* __restrict__ ycT)
{
    __shared__ __bf16 uts[32768];          // 64 KB: both halves
    __shared__ ull kkq8[544];
    __shared__ unsigned short asc[548];
    __shared__ float slg[64], scb[64];
    int h = blockIdx.x;
    int t = threadIdx.x;
    int lane = t & 63, w = t >> 6;
    int lr = lane & 15, lg = lane >> 4;

    // ---- stage BOTH halves once ----
    #pragma unroll
    for (int hf = 0; hf < 2; ++hf)
        #pragma unroll
        for (int i = 0; i < 4; ++i) {
            int chunk = i * 512 + t;          // 0..2047
            int col   = chunk >> 5;
            int l8    = (chunk & 31) << 3;
            int l8s   = l8 ^ ((col & 7) << 3);
            GLOAD16(ut + (size_t)h * 32768 + (hf * 64 + col) * 256 + l8s,
                    (char*)uts + hf * 32768 + chunk * 16);
        }

    float Dh = Dv[h];

    #pragma unroll
    for (int dir = 0; dir < 2; ++dir) {
        int dirh = dir * 512 + h;

        for (int i = t; i < 548; i += 512) {
            int d = dir ? (i - 272) : (271 - i);
            float kv = (d >= 0 && d < 256) ? kk[dirh * 256 + d] : 0.f;
            asc[i] = __builtin_bit_cast(unsigned short, (__bf16)kv);
        }
        if (t < 64)       slg[t]      = pLG[dirh * 64 + t];
        else if (t < 128) scb[t - 64] = pCB[dirh * 64 + (t - 64)];
        asm volatile("s_waitcnt lgkmcnt(0)" ::: "memory");
        __builtin_amdgcn_sched_barrier(0);
        __builtin_amdgcn_s_barrier();
        __builtin_amdgcn_sched_barrier(0);
        for (int i = t; i < 544; i += 512)
            kkq8[i] = (ull)asc[i] | ((ull)asc[i+1] << 16) | ((ull)asc[i+2] << 32)
                    | ((ull)asc[i+3] << 48);

        bf16x8 gvv[2][2];
        #pragma unroll
        for (int nt = 0; nt < 2; ++nt)
            #pragma unroll
            for (int mf = 0; mf < 2; ++mf) {
                int rt = mf ? (15 - w) : w;
                int l  = rt * 16 + lr;
                float e = dir ? (float)(256 - l) : (float)(l + 1);
                #pragma unroll
                for (int j = 0; j < 8; ++j) {
                    int n = nt * 32 + lg * 8 + j;
                    gvv[nt][mf][j] = (__bf16)(scb[n] * exp2f(e * slg[n]));
                }
            }

        if (dir == 0) {
            asm volatile("s_waitcnt vmcnt(0) lgkmcnt(0)" ::: "memory");
        } else {
            asm volatile("s_waitcnt lgkmcnt(0)" ::: "memory");
        }
        __builtin_amdgcn_sched_barrier(0);
        __builtin_amdgcn_s_barrier();
        __builtin_amdgcn_sched_barrier(0);

        const ull* kq = kkq8;
        const int rt0 = w, rt1 = 15 - w;
        const int sb0 = (dir ? 272 : 271) + lg * 8 - rt0 * 16 - lr;
        const int sb1 = (dir ? 272 : 271) + lg * 8 - rt1 * 16 - lr;
        const int jhi0 = dir ? 8 : ((rt0 >> 1) + 1);
        const int jlo1 = dir ? (rt1 >> 1) : 0;
        const int jbeg = dir ? (rt0 >> 1) : 0;
        const int jend = dir ? 8 : (((rt1) >> 1) + 1);

        #pragma unroll
        for (int hf = 0; hf < 2; ++hf) {
            char* ub = (char*)uts + hf * 32768;

            f32x4 acc[2][4] = {};

            for (int jt = jbeg; jt < jend; ++jt) {
                bf16x8 bv[4];
                #pragma unroll
                for (int n = 0; n < 4; ++n) {
                    int col = n * 16 + lr;
                    bv[n] = *(const bf16x8*)(ub + col * 512
                              + (((jt * 4 + lg) ^ (col & 7)) << 4));
                }
                if (dir ? true : (jt < jhi0)) {
                    int si = sb0 + jt * 32;
                    ull lo = kq[si], hi = kq[si + 4];
                    bf16x8 av;
                    ((ull*)&av)[0] = lo; ((ull*)&av)[1] = hi;
                    __builtin_amdgcn_s_setprio(1);
                    #pragma unroll
                    for (int n = 0; n < 4; ++n)
                        acc[0][n] = __builtin_amdgcn_mfma_f32_16x16x32_bf16(av, bv[n], acc[0][n], 0, 0, 0);
                    __builtin_amdgcn_s_setprio(0);
                }
                if (dir ? (jt >= jlo1) : true) {
                    int si = sb1 + jt * 32;
                    ull lo = kq[si], hi = kq[si + 4];
                    bf16x8 av;
                    ((ull*)&av)[0] = lo; ((ull*)&av)[1] = hi;
                    __builtin_amdgcn_s_setprio(1);
                    #pragma unroll
                    for (int n = 0; n < 4; ++n)
                        acc[1][n] = __builtin_amdgcn_mfma_f32_16x16x32_bf16(av, bv[n], acc[1][n], 0, 0, 0);
                    __builtin_amdgcn_s_setprio(0);
                }
            }

            #pragma unroll
            for (int nt = 0; nt < 2; ++nt) {
                bf16x8 bs[4];
                #pragma unroll
                for (int n = 0; n < 4; ++n) {
                    int colg = (hf * 4 + n) * 16 + lr;
                    int nq0  = nt * 8 + lg * 2;
                    const __bf16* sp = S + ((size_t)((dir * 512 + h) * 16 + nq0) * 128 + colg) * 4;
                    bf16x4 s0 = *(const bf16x4*)(sp);
                    bf16x4 s1 = *(const bf16x4*)(sp + 512);
                    #pragma unroll
                    for (int j = 0; j < 4; ++j) { bs[n][j] = s0[j]; bs[n][4 + j] = s1[j]; }
                }
                __builtin_amdgcn_s_setprio(1);
                #pragma unroll
                for (int mf = 0; mf < 2; ++mf)
                    #pragma unroll
                    for (int n = 0; n < 4; ++n)
                        acc[mf][n] = __builtin_amdgcn_mfma_f32_16x16x32_bf16(gvv[nt][mf], bs[n], acc[mf][n], 0, 0, 0);
                __builtin_amdgcn_s_setprio(0);
            }

            #pragma unroll
            for (int mf = 0; mf < 2; ++mf) {
                int rt = mf ? rt1 : rt0;
                int l0 = rt * 16 + lg * 4;
                #pragma unroll
                for (int n = 0; n < 4; ++n) {
                    int col = n * 16 + lr;
                    bf16x4 uv = *(const bf16x4*)(ub + col * 512
                                 + ((((l0 >> 3) ^ (col & 7)) << 4) | ((l0 & 7) * 2)));
                    bf16x4 o;
                    #pragma unroll
                    for (int r = 0; r < 4; ++r)
                        o[r] = (__bf16)(acc[mf][n][r] + Dh * (float)uv[r]);
                    *(bf16x4*)(ycT + (size_t)dirh * 32768 + (hf * 64 + col) * 256 + l0) = o;
                }
            }
        }
    }
}

// ---------------- K4 v11 (R24-verified): single-barrier/iter, 2A+4B ring ----------------
__global__ __launch_bounds__(256, 2) void k_gemm(
    const __bf16* __restrict__ ycT, const __bf16* __restrict__ B,
    const float* __restrict__ bias, float* __restrict__ out)
{
    __shared__ __bf16 As[2][4][128][8];    // 16 KB
    __shared__ __bf16 Bs[4][256][32];      // 64 KB
    int t  = threadIdx.x;
    int l  = t & 63, w = t >> 6;
    int lr = l & 15, lg = l >> 4;
    int bid   = blockIdx.y * 2 + blockIdx.x;
    int swzid = (bid & 7) * 64 + (bid >> 3);
    int mBase = (swzid >> 1) * 128;
    int nBase = (swzid & 1) * 256;
    int wr = (w >> 1) * 64, wc = (w & 1) * 128;

    int sT  = t & 15;           // m-octet
    int sp  = t >> 4;           // k-pair 0..15 (k = 2sp, 2sp+1)
    int swz  = (sT & 7) << 4;
    int kgrp = sp >> 2;
    int keb  = (sp & 3) * 4;

    f32x4 acc[4][8] = {};
    const __bf16* aptr = ycT + mBase + sT * 8;

#define STAGE_A(abuf, va0, va1) do { \
    char* AsB_ = (char*)&As[0][0][0][0] + (abuf) * 8192; \
    _Pragma("unroll") \
    for (int i = 0; i < 8; ++i) { \
        unsigned v_ = (unsigned)(unsigned short)(va0)[i] \
                    | ((unsigned)(unsigned short)(va1)[i] << 16); \
        int off_ = ((kgrp * 128 + sT * 8 + i) * 16 + keb) ^ swz; \
        *(unsigned*)(AsB_ + off_) = v_; \
    } } while (0)

#define STAGE_B(bbuf, kt_) do { \
    char* BsB_ = (char*)&Bs[0][0][0] + (bbuf) * 16384; \
    _Pragma("unroll") \
    for (int i = 0; i < 4; ++i) { \
        int chunk_ = i * 256 + t; \
        int row_ = chunk_ >> 2, kq_ = chunk_ & 3; \
        int kqs_ = kq_ ^ ((row_ >> 1) & 3); \
        GLOAD16(B + (size_t)(nBase + row_) * K_GEMM + (kt_) + kqs_ * 8, \
                BsB_ + chunk_ * 16); \
    } } while (0)

#define COMPUTE(abuf, bbuf) do { \
    char* AsB_ = (char*)&As[0][0][0][0] + (abuf) * 8192; \
    char* BsB_ = (char*)&Bs[0][0][0] + (bbuf) * 16384; \
    bf16x8 af_[4], bfv_[8]; \
    _Pragma("unroll") \
    for (int m = 0; m < 4; ++m) { \
        int row_ = wr + m * 16 + lr; \
        int off_ = ((lg * 128 + row_) * 16) ^ (((row_ >> 3) & 7) << 4); \
        af_[m] = *(const bf16x8*)(AsB_ + off_); \
    } \
    _Pragma("unroll") \
    for (int n = 0; n < 8; ++n) { \
        int row_ = wc + n * 16 + lr; \
        bfv_[n] = *(const bf16x8*)(BsB_ + row_ * 64 \
                    + ((lg * 16) ^ (((row_ >> 1) & 3) << 4))); \
    } \
    __builtin_amdgcn_s_setprio(1); \
    _Pragma("unroll") \
    for (int m = 0; m < 4; ++m) \
        _Pragma("unroll") \
        for (int n = 0; n < 8; ++n) \
            acc[m][n] = __builtin_amdgcn_mfma_f32_16x16x32_bf16(af_[m], bfv_[n], acc[m][n], 0, 0, 0); \
    __builtin_amdgcn_s_setprio(0); \
    } while (0)

    // ---- prologue: A-regs(0); B(0)->buf0, B(1)->buf1 issued ----
    u16x8 a0 = *(const u16x8*)(aptr + (size_t)(2 * sp) * 32768);
    u16x8 a1 = *(const u16x8*)(aptr + (size_t)(2 * sp + 1) * 32768);
    STAGE_B(0, 0);
    STAGE_B(1, 32);

    int ab = 0;
    for (int i = 0; i < 30; ++i) {                 // kt = 32*i
        int kt = i * 32;
        STAGE_A(ab, a0, a1);                       // waits prev A-regs (compiler vmcnt)
        a0 = *(const u16x8*)(aptr + (size_t)(kt + 32 + 2 * sp) * 32768);
        a1 = *(const u16x8*)(aptr + (size_t)(kt + 32 + 2 * sp + 1) * 32768);
        STAGE_B((i + 2) & 3, kt + 64);
        asm volatile("s_waitcnt vmcnt(10) lgkmcnt(0)" ::: "memory");
        __builtin_amdgcn_sched_barrier(0);
        __builtin_amdgcn_s_barrier();              // the ONLY barrier this iter
        __builtin_amdgcn_sched_barrier(0);
        COMPUTE(ab, i & 3);
        ab ^= 1;
    }
    // ---- peel i=30 (kt=960): no new B ----
    STAGE_A(ab, a0, a1);
    a0 = *(const u16x8*)(aptr + (size_t)(992 + 2 * sp) * 32768);
    a1 = *(const u16x8*)(aptr + (size_t)(992 + 2 * sp + 1) * 32768);
    asm volatile("s_waitcnt vmcnt(6) lgkmcnt(0)" ::: "memory");
    __builtin_amdgcn_sched_barrier(0);
    __builtin_amdgcn_s_barrier();
    __builtin_amdgcn_sched_barrier(0);
    COMPUTE(ab, 30 & 3);
    ab ^= 1;
    // ---- peel i=31 (kt=992): drain all ----
    STAGE_A(ab, a0, a1);
    asm volatile("s_waitcnt vmcnt(0) lgkmcnt(0)" ::: "memory");
    __builtin_amdgcn_sched_barrier(0);
    __builtin_amdgcn_s_barrier();
    __builtin_amdgcn_sched_barrier(0);
    COMPUTE(ab, 31 & 3);

#undef STAGE_A
#undef STAGE_B
#undef COMPUTE

    #pragma unroll
    for (int n = 0; n < 8; ++n) {
        int colg = nBase + wc + n * 16 + lr;
        float bv = bias[colg];
        #pragma unroll
        for (int m = 0; m < 4; ++m) {
            int rowg = mBase + wr + m * 16 + lg * 4;
            #pragma unroll
            for (int r = 0; r < 4; ++r)
                out[(size_t)(rowg + r) * H_DIM + colg] = acc[m][n][r] + bv;
        }
    }
}

extern "C" void kernel_launch(void* const* d_in, const int* in_sizes, int n_in,
                              void* d_out, int out_size, void* d_ws, size_t ws_size,
                              hipStream_t stream)
{
    const float* u       = (const float*)d_in[0];
    const float* A_log   = (const float*)d_in[1];
    const float* Bv      = (const float*)d_in[2];
    const float* C       = (const float*)d_in[3];
    const float* D       = (const float*)d_in[4];
    const float* log_dt  = (const float*)d_in[5];
    const float* A_log_r = (const float*)d_in[6];
    const float* B_r     = (const float*)d_in[7];
    const float* C_r     = (const float*)d_in[8];
    const float* W_bi    = (const float*)d_in[9];
    const float* b_bi    = (const float*)d_in[10];
    float* out = (float*)d_out;

    char* ws = (char*)d_ws;
    float* pCB  = (float*)(ws + 0x040000);
    float* pPW  = (float*)(ws + 0x080000);
    float* pLG  = (float*)(ws + 0x0C0000);
    float* kk   = (float*)(ws + 0x100000);   // 1 MiB
    __bf16* Wbf = (__bf16*)(ws + 0x200000);  // 1 MiB
    __bf16* S   = (__bf16*)(ws + 0x300000);  // 16 MiB (S2 layout, scanned)
    __bf16* ut  = (__bf16*)(ws + 0x1300000); // 32 MiB
    __bf16* ycT = (__bf16*)(ws + 0x3300000); // 64 MiB  (end 115 MiB)

    k_ut   <<<9216, 256, 0, stream>>>(u, ut, W_bi, Wbf,
                                      A_log, Bv, C, log_dt, A_log_r, B_r, C_r,
                                      kk, pLG, pCB, pPW);
    k_state<<<512,  512, 0, stream>>>(ut, pLG, pPW, S);
    k_conv <<<512,  512, 0, stream>>>(kk, pLG, pCB, D, ut, S, ycT);
    dim3 g(2, 256);
    k_gemm <<<g,    256, 0, stream>>>(ycT, Wbf, b_bi, out);
}